// Round 6
// baseline (94.127 us; speedup 1.0000x reference)
//
#include <hip/hip_runtime.h>
#include <math.h>

#define IN_DIM 5
constexpr int B = 8192;
constexpr int N = 100;
constexpr float DT     = 0.01f;
constexpr float MU_DT  = 0.001f;
constexpr float NU     = 0.2f;
constexpr float SIGMA  = 0.3f;
constexpr float BN_EPS = 1e-5f;
constexpr float FLOORV = 1e-4f;

typedef __attribute__((ext_vector_type(8))) short short8;
typedef __attribute__((ext_vector_type(4))) float f32x4;

// truncation-based bf16 split: h = hi + lo with |err| ~ 2^-16 |h|
__device__ __forceinline__ void bf16_split(float h, short& hi, short& lo) {
    unsigned int ub = __builtin_bit_cast(unsigned int, h);
    hi = (short)(ub >> 16);
    float hif = __builtin_bit_cast(float, ub & 0xffff0000u);
    float l = h - hif;
    lo = (short)(__builtin_bit_cast(unsigned int, l) >> 16);
}

// sum over each aligned 16-lane group via DPP (VALU only, no DS pipe)
__device__ __forceinline__ float red16(float v) {
#if __has_builtin(__builtin_amdgcn_update_dpp)
    int x;
    x = __builtin_amdgcn_update_dpp(0, __builtin_bit_cast(int, v), 0xB1, 0xF, 0xF, false);
    v += __builtin_bit_cast(float, x);
    x = __builtin_amdgcn_update_dpp(0, __builtin_bit_cast(int, v), 0x4E, 0xF, 0xF, false);
    v += __builtin_bit_cast(float, x);
    x = __builtin_amdgcn_update_dpp(0, __builtin_bit_cast(int, v), 0x141, 0xF, 0xF, false);
    v += __builtin_bit_cast(float, x);
    x = __builtin_amdgcn_update_dpp(0, __builtin_bit_cast(int, v), 0x140, 0xF, 0xF, false);
    v += __builtin_bit_cast(float, x);
    return v;
#else
    v += __shfl_xor(v, 1);
    v += __shfl_xor(v, 2);
    v += __shfl_xor(v, 4);
    v += __shfl_xor(v, 8);
    return v;
#endif
}

// ---------------------------------------------------------------------------
// Kernel 1: batch-norm stats (unchanged).
// ws[0..4]=alpha, ws[5..9]=beta', ws[10..14]=alphac, ws[15..19]=betac'
// ---------------------------------------------------------------------------
__global__ __launch_bounds__(1024) void bn_stats_kernel(
    const float* __restrict__ tv,
    const float* __restrict__ g1, const float* __restrict__ be1,
    const float* __restrict__ g2, const float* __restrict__ be2,
    float* __restrict__ ws)
{
    const int t = threadIdx.x;
    float s[IN_DIM] = {0.f, 0.f, 0.f, 0.f, 0.f};
    float q[IN_DIM] = {0.f, 0.f, 0.f, 0.f, 0.f};
    for (int r = t; r < B; r += 1024) {
        const float* row = tv + r * IN_DIM;
#pragma unroll
        for (int k = 0; k < IN_DIM; ++k) {
            const float v = row[k];
            s[k] += v;
            q[k] += v * v;
        }
    }
#pragma unroll
    for (int k = 0; k < IN_DIM; ++k) {
#pragma unroll
        for (int off = 32; off >= 1; off >>= 1) {
            s[k] += __shfl_xor(s[k], off);
            q[k] += __shfl_xor(q[k], off);
        }
    }
    __shared__ float red[16][2 * IN_DIM];
    const int w = t >> 6, lane = t & 63;
    if (lane == 0) {
#pragma unroll
        for (int k = 0; k < IN_DIM; ++k) {
            red[w][k] = s[k];
            red[w][IN_DIM + k] = q[k];
        }
    }
    __syncthreads();
    if (t == 0) {
#pragma unroll
        for (int k = 0; k < IN_DIM; ++k) {
            float S = 0.f, Q = 0.f;
            for (int u = 0; u < 16; ++u) { S += red[u][k]; Q += red[u][IN_DIM + k]; }
            const float mean = S / (float)B;
            const float var  = Q / (float)B - mean * mean;
            const float inv  = 1.0f / sqrtf(var + BN_EPS);
            const float a1 = inv * g1[k];
            const float a2 = inv * g2[k];
            ws[k]          = a1;
            ws[IN_DIM + k] = be1[k] - mean * a1;
            ws[10 + k]     = a2;
            ws[15 + k]     = be2[k] - mean * a2;
        }
    }
}

// ---------------------------------------------------------------------------
// Kernel 2: simulation. Block = 128 thr = 2 waves over the SAME 16 samples.
// wave = mlp (0: pi-MLP, 1: c-MLP). Each wave runs its FULL MLP: layer-1 16
// units/lane (each (unit,sample) computed exactly once — zero duplication),
// 24 MFMAs as 8 independent 3-deep chains, DPP reduce. ONE barrier per step:
// both waves publish their head scalar into a double-buffered ex slot before
// the barrier and read the pair after it. (Hazard note: a wave can only reach
// the same ex buffer again after passing the next barrier, which the partner
// gates — so double-buffering + 1 barrier is race-free.)
// All per-step inputs pre-staged in LDS; trajectory in LDS with coalesced
// epilogue write. Zero global ops inside the loop.
// ---------------------------------------------------------------------------
__global__ __launch_bounds__(128, 1) void sim_kernel(
    const float* __restrict__ bm, const float* __restrict__ cn,
    const float* __restrict__ typeVec,
    const float* __restrict__ mx, const float* __restrict__ mc,
    const float* __restrict__ initial,
    const float* __restrict__ w1, const float* __restrict__ b1,
    const float* __restrict__ w2, const float* __restrict__ b2,
    const float* __restrict__ w3, const float* __restrict__ b3,
    const float* __restrict__ wc1, const float* __restrict__ bc1,
    const float* __restrict__ wc2, const float* __restrict__ bc2,
    const float* __restrict__ wc3, const float* __restrict__ bc3,
    const float* __restrict__ ws, float* __restrict__ out)
{
    const int tid = threadIdx.x;
    const int mlp = tid >> 6;        // wave id: 0 = pi-MLP, 1 = c-MLP
    const int l   = tid & 63;
    const int s   = l & 15;          // sample (A-row) / unit-col index
    const int g   = l >> 4;          // k-octet / D-row group
    const int b0  = blockIdx.x * 16;

    __shared__ float4 SI[N][16];     // [step][sample] = {bm, dcn, mx, mc}
    __shared__ float  traj[N + 1][16];
    __shared__ float2 ex[2][16];     // [buf][sample] = {pi, c_logit}

    // ---- stage per-step inputs, coalesced ----
#pragma unroll
    for (int k = 0; k < 16; ++k) {
        const int f  = tid + 128 * k;       // < 2048
        const int ss = f >> 7;
        const int ii = f & 127;
        if (ii < N) {
            const size_t r = (size_t)(b0 + ss);
            const float vb = bm[r * N + ii];
            const float c0 = cn[r * (N + 1) + ii];
            const float c1 = cn[r * (N + 1) + ii + 1];
            const float vx = mx[r * (N + 1) + ii];
            const float vc = mc[r * N + ii];
            SI[ii][ss] = make_float4(vb, c1 - c0, vx, vc);
        }
    }

    // ---- this wave's MLP parameter set ----
    const float* W1 = mlp ? wc1 : w1;
    const float* B1 = mlp ? bc1 : b1;
    const float* W2 = mlp ? wc2 : w2;
    const float* B2 = mlp ? bc2 : b2;
    const float* W3 = mlp ? wc3 : w3;
    const float* B3 = mlp ? bc3 : b3;
    const float* alpha = ws + (mlp ? 10 : 0);
    const float* beta  = ws + (mlp ? 15 : 5);

    // ---- register-resident B-fragments of W2 (hi/lo), all 2kt x 4nt ----
    short8 Bh[2][4], Bl[2][4];
#pragma unroll
    for (int kt = 0; kt < 2; ++kt) {
#pragma unroll
        for (int nt = 0; nt < 4; ++nt) {
            short8 fh, fl;
#pragma unroll
            for (int e = 0; e < 8; ++e) {
                short hi, lo;
                bf16_split(W2[(32 * kt + 8 * g + e) * 64 + 16 * nt + s], hi, lo);
                fh[e] = hi; fl[e] = lo;
            }
            Bh[kt][nt] = fh; Bl[kt][nt] = fl;
        }
    }

    // ---- bn affine for this lane's sample; layer-1 consts (16 units) ----
    float bnv[IN_DIM];
    {
        const float* tvp = typeVec + (size_t)(b0 + s) * IN_DIM;
#pragma unroll
        for (int k = 0; k < IN_DIM; ++k)
            bnv[k] = fmaf(tvp[k], alpha[k], beta[k]);
    }
    float bs[16], wt[16], wx[16], wm[16], wcr[16];
#pragma unroll
    for (int j = 0; j < 16; ++j) {
        const int u = (j < 8) ? (8 * g + j) : (32 + 8 * g + (j - 8));
        wt[j]  = W1[5 * 64 + u];
        wx[j]  = W1[6 * 64 + u];
        wm[j]  = W1[7 * 64 + u];
        wcr[j] = W1[8 * 64 + u];
        float a = B1[u];
#pragma unroll
        for (int k = 0; k < IN_DIM; ++k) a = fmaf(bnv[k], W1[k * 64 + u], a);
        bs[j] = a;
    }
    float b2v[4], w3v[4];
#pragma unroll
    for (int nt = 0; nt < 4; ++nt) {
        b2v[nt] = B2[16 * nt + s];
        w3v[nt] = W3[16 * nt + s];
    }
    const float b3s = B3[0];
    const float x0  = initial[0];

    float x = x0;
    if (tid < 16) traj[0][tid] = x0;
    __syncthreads();

    for (int i = 0; i < N; ++i) {
        const float t = (float)i * DT;
        const float4 in = SI[i][s];   // {bm, dcn, mx, mc}

        // ---- layer-1: 16 units in-lane, relu, hi/lo split to A-frags ----
        short8 ah0, ah1, al0, al1;
#pragma unroll
        for (int j = 0; j < 16; ++j) {
            float h = bs[j];
            h = fmaf(t,    wt[j],  h);
            h = fmaf(x,    wx[j],  h);
            h = fmaf(in.z, wm[j],  h);
            h = fmaf(in.w, wcr[j], h);
            h = fmaxf(h, 0.0f);
            short hi, lo;
            bf16_split(h, hi, lo);
            if (j < 8) { ah0[j] = hi; al0[j] = lo; }
            else       { ah1[j - 8] = hi; al1[j - 8] = lo; }
        }

        // ---- layer-2 MFMA: 8 independent 3-deep chains (kt x nt) ----
        f32x4 acc0[4], acc1[4];
#pragma unroll
        for (int nt = 0; nt < 4; ++nt) {
            acc0[nt] = (f32x4){b2v[nt], b2v[nt], b2v[nt], b2v[nt]};
            acc1[nt] = (f32x4){0.f, 0.f, 0.f, 0.f};
        }
#pragma unroll
        for (int nt = 0; nt < 4; ++nt) {
            acc0[nt] = __builtin_amdgcn_mfma_f32_16x16x32_bf16(ah0, Bh[0][nt], acc0[nt], 0, 0, 0);
            acc0[nt] = __builtin_amdgcn_mfma_f32_16x16x32_bf16(al0, Bh[0][nt], acc0[nt], 0, 0, 0);
            acc0[nt] = __builtin_amdgcn_mfma_f32_16x16x32_bf16(ah0, Bl[0][nt], acc0[nt], 0, 0, 0);
            acc1[nt] = __builtin_amdgcn_mfma_f32_16x16x32_bf16(ah1, Bh[1][nt], acc1[nt], 0, 0, 0);
            acc1[nt] = __builtin_amdgcn_mfma_f32_16x16x32_bf16(al1, Bh[1][nt], acc1[nt], 0, 0, 0);
            acc1[nt] = __builtin_amdgcn_mfma_f32_16x16x32_bf16(ah1, Bl[1][nt], acc1[nt], 0, 0, 0);
        }

        // ---- layer-3: relu * w3, DPP-reduce over 16 unit-lanes ----
        float r0 = 0.f, r1 = 0.f, r2 = 0.f, r3 = 0.f;
#pragma unroll
        for (int nt = 0; nt < 4; ++nt) {
            const f32x4 fs = acc0[nt] + acc1[nt];
            r0 = fmaf(fmaxf(fs[0], 0.f), w3v[nt], r0);
            r1 = fmaf(fmaxf(fs[1], 0.f), w3v[nt], r1);
            r2 = fmaf(fmaxf(fs[2], 0.f), w3v[nt], r2);
            r3 = fmaf(fmaxf(fs[3], 0.f), w3v[nt], r3);
        }
        r0 = red16(r0); r1 = red16(r1); r2 = red16(r2); r3 = red16(r3);

        // lanes r4<4 of each g own sample 4g+r4; publish this wave's head out
        const int r4 = l & 15;
        float wv = r0;
        wv = (r4 == 1) ? r1 : wv;
        wv = (r4 == 2) ? r2 : wv;
        wv = (r4 == 3) ? r3 : wv;
        wv += b3s;
        if (r4 < 4) ((float*)&ex[i & 1][4 * g + r4])[mlp] = wv;
        __syncthreads();                       // the ONE barrier per step

        // ---- read pair, SDE update (redundant in both waves) ----
        const float2 pv = ex[i & 1][s];        // {pi, c_logit}
        const float pi_v = pv.x;
        const float c_v  = __expf(pv.y);
        const float drift = MU_DT + fmaf(NU, in.x, SIGMA * in.y);
        float xn = x + pi_v * x * drift - c_v * x * DT;
        xn = fmaxf(xn - FLOORV, 0.0f) + FLOORV;
        x = xn;

        if (tid < 16) traj[i + 1][tid] = x;
    }
    __syncthreads();

    // ---- epilogue: coalesced output write {t, x} ----
    const int TOT = 16 * (N + 1) * 2;            // 3232
#pragma unroll
    for (int k = 0; k < 26; ++k) {
        const int e = tid + 128 * k;
        if (e < TOT) {
            const int sample = e / (2 * (N + 1));
            const int r      = e - sample * (2 * (N + 1));
            const int i      = r >> 1;
            const float v    = (r & 1) ? traj[i][sample] : (float)i * DT;
            out[(size_t)b0 * (2 * (N + 1)) + e] = v;
        }
    }
}

extern "C" void kernel_launch(void* const* d_in, const int* in_sizes, int n_in,
                              void* d_out, int out_size, void* d_ws, size_t ws_size,
                              hipStream_t stream) {
    const float* bm        = (const float*)d_in[0];
    const float* cn        = (const float*)d_in[1];
    const float* typeVec   = (const float*)d_in[2];
    const float* mx        = (const float*)d_in[3];
    const float* mc        = (const float*)d_in[4];
    const float* initial   = (const float*)d_in[5];
    const float* bn_gamma  = (const float*)d_in[6];
    const float* bn_beta   = (const float*)d_in[7];
    const float* bnc_gamma = (const float*)d_in[8];
    const float* bnc_beta  = (const float*)d_in[9];
    const float* w1  = (const float*)d_in[10];
    const float* b1  = (const float*)d_in[11];
    const float* w2  = (const float*)d_in[12];
    const float* b2  = (const float*)d_in[13];
    const float* w3  = (const float*)d_in[14];
    const float* b3  = (const float*)d_in[15];
    const float* wc1 = (const float*)d_in[16];
    const float* bc1 = (const float*)d_in[17];
    const float* wc2 = (const float*)d_in[18];
    const float* bc2 = (const float*)d_in[19];
    const float* wc3 = (const float*)d_in[20];
    const float* bc3 = (const float*)d_in[21];
    float* wsp = (float*)d_ws;
    float* out = (float*)d_out;

    bn_stats_kernel<<<1, 1024, 0, stream>>>(typeVec, bn_gamma, bn_beta,
                                            bnc_gamma, bnc_beta, wsp);
    sim_kernel<<<512, 128, 0, stream>>>(bm, cn, typeVec, mx, mc, initial,
                                        w1, b1, w2, b2, w3, b3,
                                        wc1, bc1, wc2, bc2, wc3, bc3,
                                        wsp, out);
}

// Round 8
// 86.163 us; speedup vs baseline: 1.0924x; 1.0924x over previous
//
#include <hip/hip_runtime.h>
#include <math.h>

#define IN_DIM 5
constexpr int B = 8192;
constexpr int N = 100;
constexpr float DT     = 0.01f;
constexpr float MU_DT  = 0.001f;
constexpr float NU     = 0.2f;
constexpr float SIGMA  = 0.3f;
constexpr float BN_EPS = 1e-5f;
constexpr float FLOORV = 1e-4f;

typedef __attribute__((ext_vector_type(8))) short short8;
typedef __attribute__((ext_vector_type(4))) float f32x4;
typedef __attribute__((ext_vector_type(2))) float f32x2;
typedef __attribute__((ext_vector_type(4))) int   i32x4;

// truncation-based bf16 split: h = hi + lo with |err| ~ 2^-16 |h|
__device__ __forceinline__ void bf16_split(float h, short& hi, short& lo) {
    unsigned int ub = __builtin_bit_cast(unsigned int, h);
    hi = (short)(ub >> 16);
    float hif = __builtin_bit_cast(float, ub & 0xffff0000u);
    float l = h - hif;
    lo = (short)(__builtin_bit_cast(unsigned int, l) >> 16);
}

// sum over each aligned 16-lane group via DPP (VALU only, no DS pipe)
__device__ __forceinline__ float red16(float v) {
#if __has_builtin(__builtin_amdgcn_update_dpp)
    int x;
    x = __builtin_amdgcn_update_dpp(0, __builtin_bit_cast(int, v), 0xB1, 0xF, 0xF, false);
    v += __builtin_bit_cast(float, x);
    x = __builtin_amdgcn_update_dpp(0, __builtin_bit_cast(int, v), 0x4E, 0xF, 0xF, false);
    v += __builtin_bit_cast(float, x);
    x = __builtin_amdgcn_update_dpp(0, __builtin_bit_cast(int, v), 0x141, 0xF, 0xF, false);
    v += __builtin_bit_cast(float, x);
    x = __builtin_amdgcn_update_dpp(0, __builtin_bit_cast(int, v), 0x140, 0xF, 0xF, false);
    v += __builtin_bit_cast(float, x);
    return v;
#else
    v += __shfl_xor(v, 1);
    v += __shfl_xor(v, 2);
    v += __shfl_xor(v, 4);
    v += __shfl_xor(v, 8);
    return v;
#endif
}

// force a value to live in VGPRs (defeats load-sinking / remat)
#define KEEPV(v) asm volatile("" : "+v"(v))
#define KEEPS8(v) { f32x4 _kt = __builtin_bit_cast(f32x4, v); asm volatile("" : "+v"(_kt)); \
                    v = __builtin_bit_cast(short8, _kt); }

// ---------------------------------------------------------------------------
// Kernel 1: batch-norm stats (unchanged).
// ws[0..4]=alpha, ws[5..9]=beta', ws[10..14]=alphac, ws[15..19]=betac'
// ---------------------------------------------------------------------------
__global__ __launch_bounds__(1024) void bn_stats_kernel(
    const float* __restrict__ tv,
    const float* __restrict__ g1, const float* __restrict__ be1,
    const float* __restrict__ g2, const float* __restrict__ be2,
    float* __restrict__ ws)
{
    const int t = threadIdx.x;
    float s[IN_DIM] = {0.f, 0.f, 0.f, 0.f, 0.f};
    float q[IN_DIM] = {0.f, 0.f, 0.f, 0.f, 0.f};
    for (int r = t; r < B; r += 1024) {
        const float* row = tv + r * IN_DIM;
#pragma unroll
        for (int k = 0; k < IN_DIM; ++k) {
            const float v = row[k];
            s[k] += v;
            q[k] += v * v;
        }
    }
#pragma unroll
    for (int k = 0; k < IN_DIM; ++k) {
#pragma unroll
        for (int off = 32; off >= 1; off >>= 1) {
            s[k] += __shfl_xor(s[k], off);
            q[k] += __shfl_xor(q[k], off);
        }
    }
    __shared__ float red[16][2 * IN_DIM];
    const int w = t >> 6, lane = t & 63;
    if (lane == 0) {
#pragma unroll
        for (int k = 0; k < IN_DIM; ++k) {
            red[w][k] = s[k];
            red[w][IN_DIM + k] = q[k];
        }
    }
    __syncthreads();
    if (t == 0) {
#pragma unroll
        for (int k = 0; k < IN_DIM; ++k) {
            float S = 0.f, Q = 0.f;
            for (int u = 0; u < 16; ++u) { S += red[u][k]; Q += red[u][IN_DIM + k]; }
            const float mean = S / (float)B;
            const float var  = Q / (float)B - mean * mean;
            const float inv  = 1.0f / sqrtf(var + BN_EPS);
            const float a1 = inv * g1[k];
            const float a2 = inv * g2[k];
            ws[k]          = a1;
            ws[IN_DIM + k] = be1[k] - mean * a1;
            ws[10 + k]     = a2;
            ws[15 + k]     = be2[k] - mean * a2;
        }
    }
}

// ---------------------------------------------------------------------------
// Kernel 2: simulation. Block = 256 thr = 4 waves over the SAME 16 samples.
// R5 structure (proven at 84.5us): wave w = (mlp = w&1, q = w>>1).
//   layer-1: only k-units u = 32q+8g+j (j<8), A-frags exchanged via FX LDS
//   (barrier A); layer-2/3: nt in {2q,2q+1}, partials merged via ex
//   (barrier B). B-frags per-role (O pairs own A-frags, X the exchanged).
// New in R8 (each audited value-preserving):
//   - KEEPV: weights pinned in VGPRs (R5's VGPR=72 showed the compiler sank
//     weight loads into the loop -> per-step global re-fetch).
//   - pk-math layer-1 (f32x2 v_pk_fma/v_pk_max) + EXPLICIT-SHIFT bf16 pack
//     (the R7 failure was the unverified v_perm byte-order; no perm here).
//   - layer-3 vectorized f32x4; in_cur 1-step LDS prefetch.
// ---------------------------------------------------------------------------
__global__ __launch_bounds__(256, 2) void sim_kernel(
    const float* __restrict__ bm, const float* __restrict__ cn,
    const float* __restrict__ typeVec,
    const float* __restrict__ mx, const float* __restrict__ mc,
    const float* __restrict__ initial,
    const float* __restrict__ w1, const float* __restrict__ b1,
    const float* __restrict__ w2, const float* __restrict__ b2,
    const float* __restrict__ w3, const float* __restrict__ b3,
    const float* __restrict__ wc1, const float* __restrict__ bc1,
    const float* __restrict__ wc2, const float* __restrict__ bc2,
    const float* __restrict__ wc3, const float* __restrict__ bc3,
    const float* __restrict__ ws, float* __restrict__ out)
{
    const int tid = threadIdx.x;
    const int wid = tid >> 6;        // 0..3
    const int l   = tid & 63;
    const int s   = l & 15;          // sample (A-row) / unit-col index
    const int g   = l >> 4;          // k-octet / D-row group
    const int mlp = wid & 1;         // 0 = pi-MLP, 1 = c-MLP
    const int q   = wid >> 1;        // k-half (layer-1) and nt-half (layer-2/3)
    const int b0  = blockIdx.x * 16;

    __shared__ float4 SI[N][16];       // [step][sample] = {bm, dcn, mx, mc}
    __shared__ float  traj[N + 1][16];
    __shared__ float4 ex[16];          // [sample] = partials {w0,w1,w2,w3}
    __shared__ short8 FX[2][2][2][64]; // [mlp][q][hi/lo][lane] A-frag exchange

    // ---- stage per-step inputs, coalesced ----
#pragma unroll
    for (int k = 0; k < 8; ++k) {
        const int f  = tid + 256 * k;       // < 2048
        const int ss = f >> 7;
        const int ii = f & 127;
        if (ii < N) {
            const size_t r = (size_t)(b0 + ss);
            const float vb = bm[r * N + ii];
            const float c0 = cn[r * (N + 1) + ii];
            const float c1 = cn[r * (N + 1) + ii + 1];
            const float vx = mx[r * (N + 1) + ii];
            const float vc = mc[r * N + ii];
            SI[ii][ss] = make_float4(vb, c1 - c0, vx, vc);
        }
    }

    // ---- this wave's MLP parameter set ----
    const float* W1 = mlp ? wc1 : w1;
    const float* B1 = mlp ? bc1 : b1;
    const float* W2 = mlp ? wc2 : w2;
    const float* B2 = mlp ? bc2 : b2;
    const float* W3 = mlp ? wc3 : w3;
    const float* B3 = mlp ? bc3 : b3;
    const float* alpha = ws + (mlp ? 10 : 0);
    const float* beta  = ws + (mlp ? 15 : 5);

    // ---- B-fragments of W2 (hi/lo), per-role: O = kt=q, X = kt=1-q ----
    short8 BhO[2], BlO[2], BhX[2], BlX[2];
#pragma unroll
    for (int ntl = 0; ntl < 2; ++ntl) {
        const int nt = 2 * q + ntl;
        short8 fhO, flO, fhX, flX;
#pragma unroll
        for (int e = 0; e < 8; ++e) {
            short hi, lo;
            bf16_split(W2[(32 * q + 8 * g + e) * 64 + 16 * nt + s], hi, lo);
            fhO[e] = hi; flO[e] = lo;
            bf16_split(W2[(32 * (1 - q) + 8 * g + e) * 64 + 16 * nt + s], hi, lo);
            fhX[e] = hi; flX[e] = lo;
        }
        BhO[ntl] = fhO; BlO[ntl] = flO;
        BhX[ntl] = fhX; BlX[ntl] = flX;
    }

    // ---- bn affine for this lane's sample; layer-1 consts as f32x2 pairs ----
    float bnv[IN_DIM];
    {
        const float* tvp = typeVec + (size_t)(b0 + s) * IN_DIM;
#pragma unroll
        for (int k = 0; k < IN_DIM; ++k)
            bnv[k] = fmaf(tvp[k], alpha[k], beta[k]);
    }
    // pair p covers units j = 2p, 2p+1; u = 32q + 8g + j (own 8 units only)
    f32x2 bs2[4], wt2[4], wx2[4], wm2[4], wr2[4];
#pragma unroll
    for (int p = 0; p < 4; ++p) {
#pragma unroll
        for (int c = 0; c < 2; ++c) {
            const int j = 2 * p + c;
            const int u = 32 * q + 8 * g + j;
            wt2[p][c] = W1[5 * 64 + u];
            wx2[p][c] = W1[6 * 64 + u];
            wm2[p][c] = W1[7 * 64 + u];
            wr2[p][c] = W1[8 * 64 + u];
            float a = B1[u];
#pragma unroll
            for (int k = 0; k < IN_DIM; ++k) a = fmaf(bnv[k], W1[k * 64 + u], a);
            bs2[p][c] = a;
        }
    }
    f32x2 b2v, w3v;
#pragma unroll
    for (int ntl = 0; ntl < 2; ++ntl) {
        const int nt = 2 * q + ntl;
        b2v[ntl] = B2[16 * nt + s];
        w3v[ntl] = W3[16 * nt + s];
    }
    float b3s = B3[0];
    const float x0 = initial[0];

    // ---- pin all weights in VGPRs (no per-step reload) ----
#pragma unroll
    for (int ntl = 0; ntl < 2; ++ntl) {
        KEEPS8(BhO[ntl]); KEEPS8(BlO[ntl]); KEEPS8(BhX[ntl]); KEEPS8(BlX[ntl]);
    }
#pragma unroll
    for (int p = 0; p < 4; ++p) {
        KEEPV(bs2[p]); KEEPV(wt2[p]); KEEPV(wx2[p]); KEEPV(wm2[p]); KEEPV(wr2[p]);
    }
    KEEPV(b2v); KEEPV(w3v); KEEPV(b3s);

    float x = x0;
    if (tid < 16) traj[0][tid] = x0;
    __syncthreads();

    float4 in_cur = SI[0][s];

    for (int i = 0; i < N; ++i) {
        const float t = (float)i * DT;
        const float4 in = in_cur;              // {bm, dcn, mx, mc}
        if (i + 1 < N) in_cur = SI[i + 1][s];  // prefetch next step

        // ---- layer-1: 8 own units as 4 pk-pairs, relu, explicit bf16 pack ----
        const f32x2 t2  = {t, t};
        const f32x2 x2  = {x, x};
        const f32x2 mx2 = {in.z, in.z};
        const f32x2 mc2 = {in.w, in.w};
        const f32x2 z2  = {0.f, 0.f};
        unsigned int hp[4], lp[4];
#pragma unroll
        for (int p = 0; p < 4; ++p) {
            f32x2 h = __builtin_elementwise_fma(wt2[p], t2, bs2[p]);
            h = __builtin_elementwise_fma(wx2[p], x2, h);
            h = __builtin_elementwise_fma(wm2[p], mx2, h);
            h = __builtin_elementwise_fma(wr2[p], mc2, h);
            h = __builtin_elementwise_max(h, z2);
            const unsigned int u0 = __builtin_bit_cast(unsigned int, h[0]);
            const unsigned int u1 = __builtin_bit_cast(unsigned int, h[1]);
            hp[p] = (u0 >> 16) | (u1 & 0xffff0000u);   // {bf16(h1) : bf16(h0)}
            const float t0 = __builtin_bit_cast(float, u0 & 0xffff0000u);
            const float t1 = __builtin_bit_cast(float, u1 & 0xffff0000u);
            const float r0f = h[0] - t0;
            const float r1f = h[1] - t1;
            lp[p] = (__builtin_bit_cast(unsigned int, r0f) >> 16) |
                    (__builtin_bit_cast(unsigned int, r1f) & 0xffff0000u);
        }
        const short8 oh = __builtin_bit_cast(short8, (i32x4){(int)hp[0], (int)hp[1], (int)hp[2], (int)hp[3]});
        const short8 ol = __builtin_bit_cast(short8, (i32x4){(int)lp[0], (int)lp[1], (int)lp[2], (int)lp[3]});

        // exchange A-frags with partner wave (same mlp, other q)
        FX[mlp][q][0][l] = oh;
        FX[mlp][q][1][l] = ol;
        __syncthreads();                       // barrier A
        const short8 xh = FX[mlp][1 - q][0][l];
        const short8 xl = FX[mlp][1 - q][1][l];

        // ---- layer-2 MFMA: two 3-deep chains per ntl (own-kt / other-kt) ----
        f32x4 acc0[2], acc1[2];
#pragma unroll
        for (int ntl = 0; ntl < 2; ++ntl) {
            acc0[ntl] = (f32x4){b2v[ntl], b2v[ntl], b2v[ntl], b2v[ntl]};
            acc1[ntl] = (f32x4){0.f, 0.f, 0.f, 0.f};
        }
#pragma unroll
        for (int ntl = 0; ntl < 2; ++ntl) {
            acc0[ntl] = __builtin_amdgcn_mfma_f32_16x16x32_bf16(oh, BhO[ntl], acc0[ntl], 0, 0, 0);
            acc0[ntl] = __builtin_amdgcn_mfma_f32_16x16x32_bf16(ol, BhO[ntl], acc0[ntl], 0, 0, 0);
            acc0[ntl] = __builtin_amdgcn_mfma_f32_16x16x32_bf16(oh, BlO[ntl], acc0[ntl], 0, 0, 0);
            acc1[ntl] = __builtin_amdgcn_mfma_f32_16x16x32_bf16(xh, BhX[ntl], acc1[ntl], 0, 0, 0);
            acc1[ntl] = __builtin_amdgcn_mfma_f32_16x16x32_bf16(xl, BhX[ntl], acc1[ntl], 0, 0, 0);
            acc1[ntl] = __builtin_amdgcn_mfma_f32_16x16x32_bf16(xh, BlX[ntl], acc1[ntl], 0, 0, 0);
        }

        // ---- layer-3 partial: relu * w3 (f32x4 pk ops), DPP-reduce ----
        f32x4 rv = (f32x4){0.f, 0.f, 0.f, 0.f};
        const f32x4 z4 = (f32x4){0.f, 0.f, 0.f, 0.f};
#pragma unroll
        for (int ntl = 0; ntl < 2; ++ntl) {
            const f32x4 fs  = acc0[ntl] + acc1[ntl];
            const f32x4 rel = __builtin_elementwise_max(fs, z4);
            const f32x4 wsp = (f32x4){w3v[ntl], w3v[ntl], w3v[ntl], w3v[ntl]};
            rv = __builtin_elementwise_fma(rel, wsp, rv);
        }
        const float r0 = red16(rv[0]);
        const float r1 = red16(rv[1]);
        const float r2 = red16(rv[2]);
        const float r3 = red16(rv[3]);

        // lanes r4<4 of each g own sample 4g+r4; publish this wave's partial
        const int r4 = l & 15;
        float wv = r0;
        wv = (r4 == 1) ? r1 : wv;
        wv = (r4 == 2) ? r2 : wv;
        wv = (r4 == 3) ? r3 : wv;
        if (q == 0) wv += b3s;    // bias counted once per MLP
        if (r4 < 4) ((float*)&ex[4 * g + r4])[wid] = wv;
        __syncthreads();                       // barrier B

        // ---- merge partials, SDE update (redundant in all 4 waves) ----
        const float4 pv = ex[s];   // {pi_q0, cl_q0, pi_q1, cl_q1}
        const float pi_v = pv.x + pv.z;
        const float c_v  = __expf(pv.y + pv.w);
        const float drift = MU_DT + fmaf(NU, in.x, SIGMA * in.y);
        float xn = x + pi_v * x * drift - c_v * x * DT;
        xn = fmaxf(xn - FLOORV, 0.0f) + FLOORV;
        x = xn;

        if (tid < 16) traj[i + 1][tid] = x;
    }
    __syncthreads();

    // ---- epilogue: coalesced output write {t, x} ----
    const int TOT = 16 * (N + 1) * 2;            // 3232
#pragma unroll
    for (int k = 0; k < 13; ++k) {
        const int e = tid + 256 * k;
        if (e < TOT) {
            const int sample = e / (2 * (N + 1));
            const int r      = e - sample * (2 * (N + 1));
            const int i      = r >> 1;
            const float v    = (r & 1) ? traj[i][sample] : (float)i * DT;
            out[(size_t)b0 * (2 * (N + 1)) + e] = v;
        }
    }
}

extern "C" void kernel_launch(void* const* d_in, const int* in_sizes, int n_in,
                              void* d_out, int out_size, void* d_ws, size_t ws_size,
                              hipStream_t stream) {
    const float* bm        = (const float*)d_in[0];
    const float* cn        = (const float*)d_in[1];
    const float* typeVec   = (const float*)d_in[2];
    const float* mx        = (const float*)d_in[3];
    const float* mc        = (const float*)d_in[4];
    const float* initial   = (const float*)d_in[5];
    const float* bn_gamma  = (const float*)d_in[6];
    const float* bn_beta   = (const float*)d_in[7];
    const float* bnc_gamma = (const float*)d_in[8];
    const float* bnc_beta  = (const float*)d_in[9];
    const float* w1  = (const float*)d_in[10];
    const float* b1  = (const float*)d_in[11];
    const float* w2  = (const float*)d_in[12];
    const float* b2  = (const float*)d_in[13];
    const float* w3  = (const float*)d_in[14];
    const float* b3  = (const float*)d_in[15];
    const float* wc1 = (const float*)d_in[16];
    const float* bc1 = (const float*)d_in[17];
    const float* wc2 = (const float*)d_in[18];
    const float* bc2 = (const float*)d_in[19];
    const float* wc3 = (const float*)d_in[20];
    const float* bc3 = (const float*)d_in[21];
    float* wsp = (float*)d_ws;
    float* out = (float*)d_out;

    bn_stats_kernel<<<1, 1024, 0, stream>>>(typeVec, bn_gamma, bn_beta,
                                            bnc_gamma, bnc_beta, wsp);
    sim_kernel<<<512, 256, 0, stream>>>(bm, cn, typeVec, mx, mc, initial,
                                        w1, b1, w2, b2, w3, b3,
                                        wc1, bc1, wc2, bc2, wc3, bc3,
                                        wsp, out);
}